// Round 1
// baseline (1526.048 us; speedup 1.0000x reference)
//
#include <hip/hip_runtime.h>
#include <hip/hip_bf16.h>

// Problem constants
#define NN 20000     // nodes
#define DD 32        // neighbors per node
#define IN_DIM 3
#define HH 64        // hidden
#define G4 256       // 4*H

// ---------- fast activations (fp32, ~1ulp rcp/exp; safe at extreme inputs) ----------
__device__ __forceinline__ float fast_sigmoid(float x) {
    // exp(-x) -> inf for very negative x gives 1/inf = 0: correct limit
    return __builtin_amdgcn_rcpf(1.0f + __expf(-x));
}
__device__ __forceinline__ float fast_tanh(float x) {
    float ax = __builtin_fabsf(x);
    float e  = __expf(-2.0f * ax);            // in (0,1], no overflow
    float r  = (1.0f - e) * __builtin_amdgcn_rcpf(1.0f + e);
    return __builtin_copysignf(r, x);
}

// ---------- kernel 0: sort each node's 32 neighbor ids ascending (bitonic, in-register) ----------
__global__ void sort_nbrs_kernel(const int* __restrict__ nbr, int* __restrict__ out) {
    int n = blockIdx.x * blockDim.x + threadIdx.x;
    if (n >= NN) return;
    int v[32];
    const int4* src = (const int4*)(nbr + n * 32);
    #pragma unroll
    for (int i = 0; i < 8; i++) {
        int4 t = src[i];
        v[4*i] = t.x; v[4*i+1] = t.y; v[4*i+2] = t.z; v[4*i+3] = t.w;
    }
    #pragma unroll
    for (int k = 2; k <= 32; k <<= 1) {
        #pragma unroll
        for (int j = k >> 1; j > 0; j >>= 1) {
            #pragma unroll
            for (int i = 0; i < 32; i++) {
                int ixj = i ^ j;
                if (ixj > i) {
                    bool up = (i & k) == 0;
                    int a = v[i], b = v[ixj];
                    bool sw = up ? (a > b) : (a < b);
                    if (sw) { v[i] = b; v[ixj] = a; }
                }
            }
        }
    }
    int4* dst = (int4*)(out + n * 32);
    #pragma unroll
    for (int i = 0; i < 8; i++) dst[i] = make_int4(v[4*i], v[4*i+1], v[4*i+2], v[4*i+3]);
}

// ---------- kernel 1: xproj[n][j] = sum_k h[n][k] * W_ih[j][k] + b_ih[j] + b_hh[j] ----------
// block = 256 threads (one per gate column j), 16 nodes per block. 20000/16 = 1250 blocks exact.
template<int IND>
__global__ void xproj_kernel(const float* __restrict__ h, const float* __restrict__ W_ih,
                             const float* __restrict__ b_ih, const float* __restrict__ b_hh,
                             float* __restrict__ xproj) {
    const int NB = 16;
    __shared__ __align__(16) float sh[NB * IND];
    int j   = threadIdx.x;
    int nb0 = blockIdx.x * NB;

    float w[IND];
    #pragma unroll
    for (int k = 0; k < IND; k++) w[k] = W_ih[j * IND + k];
    float bs = b_ih[j] + b_hh[j];

    for (int idx = threadIdx.x; idx < NB * IND; idx += 256)
        sh[idx] = h[nb0 * IND + idx];          // contiguous, coalesced
    __syncthreads();

    #pragma unroll 4
    for (int m = 0; m < NB; m++) {
        float acc = bs;
        #pragma unroll
        for (int k = 0; k < IND; k++) acc = fmaf(sh[m * IND + k], w[k], acc);
        xproj[(nb0 + m) * G4 + j] = acc;       // coalesced over j
    }
}

// ---------- kernel 2: 32-step LSTM recurrence + combine (+ optional output head) ----------
// One wave handles 10 nodes. 2000 waves total = 500 blocks x 4 waves. 2 blocks/CU (LDS 76KB).
// LDS W layout: sW4[k*64+u] = {W_hh[u][k], W_hh[u+64][k], W_hh[u+128][k], W_hh[u+192][k]}
// so lane u's ds_read_b128 serves its 4 gate columns; reused across 10 nodes (40 FMA / 16B).
template<int IND, bool LAST>
__global__ __launch_bounds__(256, 2)
void lstm_kernel(const float* __restrict__ xproj,
                 const int*   __restrict__ nbrs,
                 const float* __restrict__ W_hh,
                 const float* __restrict__ hin,
                 const float* __restrict__ Wl,
                 const float* __restrict__ bl,
                 const float* __restrict__ W_out,
                 const float* __restrict__ b_out,
                 float* __restrict__ hout) {
    __shared__ float4 sW4[64 * 64];                  // 64 KB
    __shared__ __align__(16) float sH[4][64 * 12];   // per-wave h buffer, [k][m] rows padded to 12

    // stage W_hh (coalesced global reads over k)
    for (int idx = threadIdx.x; idx < 4096; idx += 256) {
        int u = idx >> 6, k = idx & 63;
        sW4[k * 64 + u] = make_float4(W_hh[u * 64 + k],        W_hh[(u + 64) * 64 + k],
                                      W_hh[(u + 128) * 64 + k], W_hh[(u + 192) * 64 + k]);
    }
    __syncthreads();

    const int wave = threadIdx.x >> 6;
    const int lane = threadIdx.x & 63;
    const int wid  = blockIdx.x * 4 + wave;
    const int node0 = wid * 10;
    if (node0 >= NN) return;
    float* sHw = sH[wave];

    float  c[10];
    float4 xp[10];
    #pragma unroll
    for (int m = 0; m < 10; m++) c[m] = 0.0f;
    // prefetch gather for t=0
    #pragma unroll
    for (int m = 0; m < 10; m++) {
        int idx = nbrs[(node0 + m) * DD];
        const float* row = xproj + idx * G4;
        xp[m].x = row[lane]; xp[m].y = row[lane + 64]; xp[m].z = row[lane + 128]; xp[m].w = row[lane + 192];
    }

    for (int t = 0; t < DD; t++) {
        float4 acc[10];
        #pragma unroll
        for (int m = 0; m < 10; m++) acc[m] = xp[m];
        if (t < DD - 1) {
            #pragma unroll
            for (int m = 0; m < 10; m++) {
                int idx = nbrs[(node0 + m) * DD + t + 1];
                const float* row = xproj + idx * G4;
                xp[m].x = row[lane]; xp[m].y = row[lane + 64]; xp[m].z = row[lane + 128]; xp[m].w = row[lane + 192];
            }
        }
        if (t > 0) {
            #pragma unroll 8
            for (int k = 0; k < 64; k++) {
                float4 w = sW4[k * 64 + lane];
                #pragma unroll
                for (int m = 0; m < 10; m++) {
                    float hk = sHw[k * 12 + m];
                    acc[m].x = fmaf(w.x, hk, acc[m].x);
                    acc[m].y = fmaf(w.y, hk, acc[m].y);
                    acc[m].z = fmaf(w.z, hk, acc[m].z);
                    acc[m].w = fmaf(w.w, hk, acc[m].w);
                }
            }
        }
        // pointwise LSTM update; lane u owns hidden unit u for all 10 nodes
        #pragma unroll
        for (int m = 0; m < 10; m++) {
            float ig = fast_sigmoid(acc[m].x);
            float fg = fast_sigmoid(acc[m].y);
            float gg = fast_tanh(acc[m].z);
            float og = fast_sigmoid(acc[m].w);
            float cm = fmaf(fg, c[m], ig * gg);
            c[m] = cm;
            sHw[lane * 12 + m] = og * fast_tanh(cm);   // h for next step (wave-synchronous)
        }
    }

    // ---- combine epilogue: relu([hin, agg] @ Wl^T + bl); agg[k][m] sits in sHw ----
    const int CW = IND + 64;
    float val[10];
    #pragma unroll
    for (int m = 0; m < 10; m++) val[m] = bl[lane];
    #pragma unroll
    for (int k = 0; k < IND; k++) {
        float wv = Wl[lane * CW + k];
        #pragma unroll
        for (int m = 0; m < 10; m++) val[m] = fmaf(hin[(node0 + m) * IND + k], wv, val[m]);
    }
    #pragma unroll 4
    for (int k = 0; k < 64; k++) {
        float wv = Wl[lane * CW + IND + k];
        #pragma unroll
        for (int m = 0; m < 10; m++) val[m] = fmaf(sHw[k * 12 + m], wv, val[m]);
    }

    if (!LAST) {
        #pragma unroll
        for (int m = 0; m < 10; m++) hout[(node0 + m) * 64 + lane] = fmaxf(val[m], 0.0f);
    } else {
        float wo = W_out[lane];
        float bo = b_out[0];
        #pragma unroll
        for (int m = 0; m < 10; m++) {
            float r = fmaxf(val[m], 0.0f) * wo;
            #pragma unroll
            for (int off = 32; off > 0; off >>= 1) r += __shfl_xor(r, off);
            if (lane == 0) hout[node0 + m] = r + bo;
        }
    }
}

extern "C" void kernel_launch(void* const* d_in, const int* in_sizes, int n_in,
                              void* d_out, int out_size, void* d_ws, size_t ws_size,
                              hipStream_t stream) {
    (void)in_sizes; (void)n_in; (void)out_size; (void)ws_size;
    const float* node_features = (const float*)d_in[0];
    const int*   nbr           = (const int*)d_in[1];
    const float* W_ih[3] = {(const float*)d_in[2],  (const float*)d_in[8],  (const float*)d_in[14]};
    const float* W_hh[3] = {(const float*)d_in[3],  (const float*)d_in[9],  (const float*)d_in[15]};
    const float* b_ih[3] = {(const float*)d_in[4],  (const float*)d_in[10], (const float*)d_in[16]};
    const float* b_hh[3] = {(const float*)d_in[5],  (const float*)d_in[11], (const float*)d_in[17]};
    const float* Wl[3]   = {(const float*)d_in[6],  (const float*)d_in[12], (const float*)d_in[18]};
    const float* bl[3]   = {(const float*)d_in[7],  (const float*)d_in[13], (const float*)d_in[19]};
    const float* W_out   = (const float*)d_in[20];
    const float* b_out   = (const float*)d_in[21];

    char* ws = (char*)d_ws;
    int*   nbr_s = (int*)ws;                              // 20000*32*4   = 2,560,000 B
    float* xproj = (float*)(ws + 2560000);                // 20000*256*4  = 20,480,000 B
    float* h1    = (float*)(ws + 23040000);               // 20000*64*4   = 5,120,000 B
    float* h2    = (float*)(ws + 28160000);               // 20000*64*4   = 5,120,000 B
    float* out   = (float*)d_out;

    sort_nbrs_kernel<<<(NN + 255) / 256, 256, 0, stream>>>(nbr, nbr_s);

    // layer 0 (in_d = 3)
    xproj_kernel<3><<<NN / 16, 256, 0, stream>>>(node_features, W_ih[0], b_ih[0], b_hh[0], xproj);
    lstm_kernel<3, false><<<NN / 40, 256, 0, stream>>>(xproj, nbr_s, W_hh[0], node_features,
                                                       Wl[0], bl[0], nullptr, nullptr, h1);
    // layer 1 (in_d = 64)
    xproj_kernel<64><<<NN / 16, 256, 0, stream>>>(h1, W_ih[1], b_ih[1], b_hh[1], xproj);
    lstm_kernel<64, false><<<NN / 40, 256, 0, stream>>>(xproj, nbr_s, W_hh[1], h1,
                                                        Wl[1], bl[1], nullptr, nullptr, h2);
    // layer 2 (in_d = 64) + output head fused
    xproj_kernel<64><<<NN / 16, 256, 0, stream>>>(h2, W_ih[2], b_ih[2], b_hh[2], xproj);
    lstm_kernel<64, true><<<NN / 40, 256, 0, stream>>>(xproj, nbr_s, W_hh[2], h2,
                                                       Wl[2], bl[2], W_out, b_out, out);
}

// Round 2
// 539.840 us; speedup vs baseline: 2.8269x; 2.8269x over previous
//
#include <hip/hip_runtime.h>
#include <hip/hip_bf16.h>

// Problem constants
#define NN 20000
#define NG 1250                  // node groups of 16
#define LOG2E 1.44269504088896f
#define TWOLOG2E 2.88539008177793f

typedef __attribute__((ext_vector_type(8))) short short8;   // 8 bf16 = 4 VGPRs (MFMA A/B frag)
typedef __attribute__((ext_vector_type(4))) float floatx4;  // MFMA C/D frag

__device__ __forceinline__ floatx4 MF(short8 a, short8 b, floatx4 c) {
    return __builtin_amdgcn_mfma_f32_16x16x32_bf16(a, b, c, 0, 0, 0);
}
// sigmoid with log2(e) pre-folded into the gate: 1/(1+2^-x)
__device__ __forceinline__ float sigm2(float x) {
    return __builtin_amdgcn_rcpf(1.0f + __builtin_amdgcn_exp2f(-x));
}
// tanh with 2*log2(e) pre-folded: (1-2^-|x|)/(1+2^-|x|) * sign(x)
__device__ __forceinline__ float tanh2(float x) {
    float a = __builtin_fabsf(x);
    float e = __builtin_amdgcn_exp2f(-a);
    float r = (1.0f - e) * __builtin_amdgcn_rcpf(1.0f + e);
    return __builtin_copysignf(r, x);
}
__device__ __forceinline__ unsigned short bf16r(float x) {
    return __builtin_bit_cast(unsigned short, __float2bfloat16(x));
}

// ---------- sort each node's 32 neighbors ascending; store transposed per 16-node group ----------
__global__ void sort_nbrs_kernel(const int* __restrict__ nbr, int* __restrict__ nbrT) {
    int n = blockIdx.x * blockDim.x + threadIdx.x;
    if (n >= NN) return;
    int v[32];
    const int4* src = (const int4*)(nbr + n * 32);
    #pragma unroll
    for (int i = 0; i < 8; i++) {
        int4 t = src[i];
        v[4*i] = t.x; v[4*i+1] = t.y; v[4*i+2] = t.z; v[4*i+3] = t.w;
    }
    #pragma unroll
    for (int k = 2; k <= 32; k <<= 1)
        #pragma unroll
        for (int j = k >> 1; j > 0; j >>= 1)
            #pragma unroll
            for (int i = 0; i < 32; i++) {
                int ixj = i ^ j;
                if (ixj > i) {
                    bool up = (i & k) == 0;
                    int a = v[i], b = v[ixj];
                    bool sw = up ? (a > b) : (a < b);
                    if (sw) { v[i] = b; v[ixj] = a; }
                }
            }
    int g = n >> 4, m = n & 15;
    int base = g * 512 + m;      // nbrT[g][t][m]
    #pragma unroll
    for (int t = 0; t < 32; t++) nbrT[base + t * 16] = v[t];
}

// ---------- prep: bf16 weight repack (B-frag friendly, log2e pre-folded), bias sums, padded x ----------
#define PREP_TOT (49152 + 49152 + 12288 + 12288 + 768 + 640000)
__global__ void prep_kernel(const float* __restrict__ x,
    const float* __restrict__ Wih0, const float* __restrict__ Whh0,
    const float* __restrict__ bih0, const float* __restrict__ bhh0, const float* __restrict__ Wl0,
    const float* __restrict__ Wih1, const float* __restrict__ Whh1,
    const float* __restrict__ bih1, const float* __restrict__ bhh1, const float* __restrict__ Wl1,
    const float* __restrict__ Wih2, const float* __restrict__ Whh2,
    const float* __restrict__ bih2, const float* __restrict__ bhh2, const float* __restrict__ Wl2,
    unsigned short* __restrict__ Wih_p, unsigned short* __restrict__ Whh_p,
    unsigned short* __restrict__ Wlx_p, unsigned short* __restrict__ Wlh_p,
    float* __restrict__ bsum, unsigned short* __restrict__ x32)
{
    for (int i = blockIdx.x * 256 + threadIdx.x; i < PREP_TOT; i += gridDim.x * 256) {
        int j = i;
        if (j < 49152) {                       // Wih_p: [col][k], layer0 K=32 padded from 3
            int l = j >> 14, e = j & 16383;
            if (l == 0) {
                if (e < 8192) {
                    int col = e >> 5, k = e & 31;
                    float sc = (col >= 128 && col < 192) ? TWOLOG2E : LOG2E;
                    float v = (k < 3) ? Wih0[col*3 + k] * sc : 0.f;
                    Wih_p[e] = bf16r(v);
                }
            } else {
                int col = e >> 6, k = e & 63;
                const float* W = (l == 1) ? Wih1 : Wih2;
                float sc = (col >= 128 && col < 192) ? TWOLOG2E : LOG2E;
                Wih_p[l*16384 + e] = bf16r(W[col*64 + k] * sc);
            }
            continue;
        }
        j -= 49152;
        if (j < 49152) {                       // Whh_p
            int l = j >> 14, e = j & 16383;
            int col = e >> 6, k = e & 63;
            const float* W = (l == 0) ? Whh0 : ((l == 1) ? Whh1 : Whh2);
            float sc = (col >= 128 && col < 192) ? TWOLOG2E : LOG2E;
            Whh_p[l*16384 + e] = bf16r(W[col*64 + k] * sc);
            continue;
        }
        j -= 49152;
        if (j < 12288) {                       // Wlx_p (no scale), layer0 K=32 padded from 3
            int l = j >> 12, e = j & 4095;
            if (l == 0) {
                if (e < 2048) {
                    int col = e >> 5, k = e & 31;
                    float v = (k < 3) ? Wl0[col*67 + k] : 0.f;
                    Wlx_p[e] = bf16r(v);
                }
            } else {
                int col = e >> 6, k = e & 63;
                const float* W = (l == 1) ? Wl1 : Wl2;
                Wlx_p[l*4096 + e] = bf16r(W[col*128 + k]);
            }
            continue;
        }
        j -= 12288;
        if (j < 12288) {                       // Wlh_p
            int l = j >> 12, e = j & 4095;
            int col = e >> 6, k = e & 63;
            float v = (l == 0) ? Wl0[col*67 + 3 + k]
                               : ((l == 1) ? Wl1 : Wl2)[col*128 + 64 + k];
            Wlh_p[l*4096 + e] = bf16r(v);
            continue;
        }
        j -= 12288;
        if (j < 768) {                         // bsum = (b_ih + b_hh) * scale
            int l = j >> 8, col = j & 255;
            const float* bi = (l == 0) ? bih0 : ((l == 1) ? bih1 : bih2);
            const float* bh = (l == 0) ? bhh0 : ((l == 1) ? bhh1 : bhh2);
            float sc = (col >= 128 && col < 192) ? TWOLOG2E : LOG2E;
            bsum[l*256 + col] = (bi[col] + bh[col]) * sc;
            continue;
        }
        j -= 768;
        {                                      // x32: padded bf16 node features [n][32]
            int n = j >> 5, k = j & 31;
            x32[j] = bf16r((k < 3) ? x[n*3 + k] : 0.f);
        }
    }
}

// ---------- fused LSTM-aggregate + combine, MFMA version ----------
// Block = 2 waves (wave-pair). Wave w owns gate-cols 128w..128w+127 (8 col-tiles).
// Per step: gates = gather(h_prev)[16x64]@Wih^T + h[16x64]@Whh^T + bias  (MFMA, bf16)
// i/f <-> g/o exchanged via LDS; h round-trips LDS in A-frag-major layout (1 ds_read_b128).
template<int XKC, int LASTL>
__global__ __launch_bounds__(128, 2)
void lstm_mfma_kernel(const unsigned short* __restrict__ xsrc,  // bf16 rows, stride XKC*32 shorts
                      const int* __restrict__ nbrT,
                      const unsigned short* __restrict__ Wih,   // bf16 [256][XKC*32]
                      const unsigned short* __restrict__ Whh,   // bf16 [256][64]
                      const float* __restrict__ bsum,           // [256] prescaled
                      const unsigned short* __restrict__ Wlx,   // bf16 [64][XKC*32]
                      const unsigned short* __restrict__ Wlh,   // bf16 [64][64]
                      const float* __restrict__ bl,             // [64]
                      void* __restrict__ hout)                  // bf16[n][64] or float[n][64]
{
    __shared__ unsigned short sA[1024];      // h tile in A-frag-major layout (2 KB)
    __shared__ float sX[2][1088];            // gate exchange, row stride 68 (2-way max conflicts)

    const int w    = threadIdx.x >> 6;
    const int lane = threadIdx.x & 63;
    const int q    = lane >> 4;
    const int c    = lane & 15;
    const int XS   = XKC * 32;

    // persistent weight fragments: B[k][col] = W[col][k], col = 128w + 16*tile + c, k = 32kc+8q+j
    short8 fWih[8][XKC];
    short8 fWhh[8][2];
    float  biasv[8];
    #pragma unroll
    for (int t8 = 0; t8 < 8; t8++) {
        int col = 128*w + 16*t8 + c;
        biasv[t8] = bsum[col];
        #pragma unroll
        for (int kc = 0; kc < XKC; kc++)
            fWih[t8][kc] = *(const short8*)(Wih + col*XS + kc*32 + q*8);
        #pragma unroll
        for (int kc = 0; kc < 2; kc++)
            fWhh[t8][kc] = *(const short8*)(Whh + col*64 + kc*32 + q*8);
    }

    float* sXw = sX[w];
    float* sXo = sX[1 - w];

    for (int g = blockIdx.x; g < NG; g += 512) {
        const int node0 = g * 16;
        const int* nbg = nbrT + g * 512;

        float cst[4][2];
        #pragma unroll
        for (int r = 0; r < 4; r++) { cst[r][0] = 0.f; cst[r][1] = 0.f; }
        short8 hA[2] = {};

        int idx_cur = nbg[c];
        int idx_nxt = nbg[16 + c];
        short8 xg[XKC];
        #pragma unroll
        for (int kc = 0; kc < XKC; kc++)
            xg[kc] = *(const short8*)(xsrc + (long)idx_cur * XS + kc*32 + q*8);

        #pragma unroll 1
        for (int t = 0; t < 32; t++) {
            floatx4 acc[8];
            #pragma unroll
            for (int t8 = 0; t8 < 8; t8++) {
                floatx4 a; a[0] = biasv[t8]; a[1] = biasv[t8]; a[2] = biasv[t8]; a[3] = biasv[t8];
                acc[t8] = a;
            }
            if (t > 0) {
                #pragma unroll
                for (int t8 = 0; t8 < 8; t8++) {
                    acc[t8] = MF(hA[0], fWhh[t8][0], acc[t8]);
                    acc[t8] = MF(hA[1], fWhh[t8][1], acc[t8]);
                }
            }
            #pragma unroll
            for (int t8 = 0; t8 < 8; t8++) {
                #pragma unroll
                for (int kc = 0; kc < XKC; kc++)
                    acc[t8] = MF(xg[kc], fWih[t8][kc], acc[t8]);
            }

            // prefetch next step's gathered input (in flight across pointwise + barriers)
            if (t < 31) {
                #pragma unroll
                for (int kc = 0; kc < XKC; kc++)
                    xg[kc] = *(const short8*)(xsrc + (long)idx_nxt * XS + kc*32 + q*8);
                int tn = (t + 2 < 32) ? t + 2 : 31;
                idx_nxt = nbg[tn*16 + c];
            }

            // exchange: send the two remote gates (w0 sends i,f of upper units; w1 sends g,o of lower)
            #pragma unroll
            for (int s = 0; s < 2; s++) {
                #pragma unroll
                for (int r = 0; r < 4; r++) {
                    int rb = (4*q + r)*68 + 16*s + c;
                    float va, vb;
                    if (w == 0) { va = acc[2+s][r]; vb = acc[6+s][r]; }
                    else        { va = acc[s][r];   vb = acc[4+s][r]; }
                    sXw[rb] = va; sXw[rb + 32] = vb;
                }
            }
            __syncthreads();

            // pointwise LSTM cell; cells of wave w: units u = 32w + 16s + c, rows 4q+r
            #pragma unroll
            for (int s = 0; s < 2; s++) {
                #pragma unroll
                for (int r = 0; r < 4; r++) {
                    int rb = (4*q + r)*68 + 16*s + c;
                    float b0 = sXo[rb], b1 = sXo[rb + 32];
                    float gi, gf, gg, go;
                    if (w == 0) { gi = acc[s][r];  gf = acc[4+s][r]; gg = b0;           go = b1; }
                    else        { gi = b0;         gf = b1;          gg = acc[2+s][r];  go = acc[6+s][r]; }
                    float ii = sigm2(gi), ff = sigm2(gf), G = tanh2(gg), oo = sigm2(go);
                    float cm = ff * cst[r][s] + ii * G;
                    cst[r][s] = cm;
                    float h = oo * tanh2(TWOLOG2E * cm);
                    int Lr = 4*q + r + 16*(2*s + (c >> 3));     // A-frag reader lane for k=u
                    sA[w*512 + Lr*8 + (c & 7)] = bf16r(h);
                }
            }
            __syncthreads();
            hA[0] = *(const short8*)(sA + lane*8);        // ds_read_b128: full h A-frags
            hA[1] = *(const short8*)(sA + 512 + lane*8);
        }

        // ---- combine: relu([h_in, agg] @ Wl^T + bl); agg frags = hA (step 31) ----
        short8 fx[2][XKC], fh[2][2];
        float blv[2];
        #pragma unroll
        for (int s = 0; s < 2; s++) {
            int col = 32*w + 16*s + c;
            blv[s] = bl[col];
            #pragma unroll
            for (int kc = 0; kc < XKC; kc++)
                fx[s][kc] = *(const short8*)(Wlx + col*XS + kc*32 + q*8);
            #pragma unroll
            for (int kc = 0; kc < 2; kc++)
                fh[s][kc] = *(const short8*)(Wlh + col*64 + kc*32 + q*8);
        }
        short8 hin[XKC];
        #pragma unroll
        for (int kc = 0; kc < XKC; kc++)
            hin[kc] = *(const short8*)(xsrc + (long)(node0 + c) * XS + kc*32 + q*8);

        #pragma unroll
        for (int s = 0; s < 2; s++) {
            floatx4 a; a[0] = blv[s]; a[1] = blv[s]; a[2] = blv[s]; a[3] = blv[s];
            #pragma unroll
            for (int kc = 0; kc < XKC; kc++) a = MF(hin[kc], fx[s][kc], a);
            a = MF(hA[0], fh[s][0], a);
            a = MF(hA[1], fh[s][1], a);
            #pragma unroll
            for (int r = 0; r < 4; r++) {
                float v = fmaxf(a[r], 0.0f);
                int n = node0 + 4*q + r;
                int u = 32*w + 16*s + c;
                if (LASTL) ((float*)hout)[n*64 + u] = v;
                else       ((unsigned short*)hout)[n*64 + u] = bf16r(v);
            }
        }
    }
}

// ---------- head: out[n] = relu_comb[n] . W_out + b_out ----------
__global__ void head_kernel(const float* __restrict__ hb3, const float* __restrict__ W_out,
                            const float* __restrict__ b_out, float* __restrict__ out) {
    int t = blockIdx.x * 256 + threadIdx.x;
    int n = t >> 2;
    if (n >= NN) return;
    int sub = t & 3;
    const float4* row = (const float4*)(hb3 + n*64 + sub*16);
    const float4* wv  = (const float4*)(W_out + sub*16);
    float s = 0.f;
    #pragma unroll
    for (int i = 0; i < 4; i++) {
        float4 h = row[i], wq = wv[i];
        s += h.x*wq.x + h.y*wq.y + h.z*wq.z + h.w*wq.w;
    }
    s += __shfl_xor(s, 1);
    s += __shfl_xor(s, 2);
    if (sub == 0) out[n] = s + b_out[0];
}

extern "C" void kernel_launch(void* const* d_in, const int* in_sizes, int n_in,
                              void* d_out, int out_size, void* d_ws, size_t ws_size,
                              hipStream_t stream) {
    (void)in_sizes; (void)n_in; (void)out_size; (void)ws_size;
    const float* node_features = (const float*)d_in[0];
    const int*   nbr           = (const int*)d_in[1];
    const float* Wih[3] = {(const float*)d_in[2],  (const float*)d_in[8],  (const float*)d_in[14]};
    const float* Whh[3] = {(const float*)d_in[3],  (const float*)d_in[9],  (const float*)d_in[15]};
    const float* bih[3] = {(const float*)d_in[4],  (const float*)d_in[10], (const float*)d_in[16]};
    const float* bhh[3] = {(const float*)d_in[5],  (const float*)d_in[11], (const float*)d_in[17]};
    const float* Wl[3]  = {(const float*)d_in[6],  (const float*)d_in[12], (const float*)d_in[18]};
    const float* bl[3]  = {(const float*)d_in[7],  (const float*)d_in[13], (const float*)d_in[19]};
    const float* W_out  = (const float*)d_in[20];
    const float* b_out  = (const float*)d_in[21];

    char* ws = (char*)d_ws;
    int*            nbrT  = (int*)ws;                               // 2,560,000 B
    unsigned short* x32   = (unsigned short*)(ws + 2560000);        // 1,280,000 B
    unsigned short* hb1   = (unsigned short*)(ws + 3840000);        // 2,560,000 B
    unsigned short* hb2   = (unsigned short*)(ws + 6400000);        // 2,560,000 B
    float*          hb3   = (float*)(ws + 8960000);                 // 5,120,000 B
    unsigned short* Wih_p = (unsigned short*)(ws + 14080000);       // 98,304 B
    unsigned short* Whh_p = (unsigned short*)(ws + 14178304);       // 98,304 B
    unsigned short* Wlx_p = (unsigned short*)(ws + 14276608);       // 24,576 B
    unsigned short* Wlh_p = (unsigned short*)(ws + 14301184);       // 24,576 B
    float*          bsum  = (float*)(ws + 14325760);                // 3,072 B

    prep_kernel<<<1024, 256, 0, stream>>>(node_features,
        Wih[0], Whh[0], bih[0], bhh[0], Wl[0],
        Wih[1], Whh[1], bih[1], bhh[1], Wl[1],
        Wih[2], Whh[2], bih[2], bhh[2], Wl[2],
        Wih_p, Whh_p, Wlx_p, Wlh_p, bsum, x32);
    sort_nbrs_kernel<<<(NN + 255) / 256, 256, 0, stream>>>(nbr, nbrT);

    lstm_mfma_kernel<1, 0><<<512, 128, 0, stream>>>(x32, nbrT,
        Wih_p,         Whh_p,         bsum,       Wlx_p,        Wlh_p,        bl[0], hb1);
    lstm_mfma_kernel<2, 0><<<512, 128, 0, stream>>>(hb1, nbrT,
        Wih_p + 16384, Whh_p + 16384, bsum + 256, Wlx_p + 4096, Wlh_p + 4096, bl[1], hb2);
    lstm_mfma_kernel<2, 1><<<512, 128, 0, stream>>>(hb2, nbrT,
        Wih_p + 32768, Whh_p + 32768, bsum + 512, Wlx_p + 8192, Wlh_p + 8192, bl[2], hb3);

    head_kernel<<<(NN * 4 + 255) / 256, 256, 0, stream>>>(hb3, W_out, b_out, (float*)d_out);
}

// Round 3
// 297.125 us; speedup vs baseline: 5.1360x; 1.8169x over previous
//
#include <hip/hip_runtime.h>
#include <hip/hip_bf16.h>

// Problem constants
#define NN 20000
#define NG 1250                  // node groups of 16
#define LOG2E 1.44269504088896f
#define TWOLOG2E 2.88539008177793f

typedef __attribute__((ext_vector_type(8))) short short8;   // 8 bf16 = 4 VGPRs (MFMA A/B frag)
typedef __attribute__((ext_vector_type(4))) float floatx4;  // MFMA C/D frag

__device__ __forceinline__ floatx4 MF(short8 a, short8 b, floatx4 c) {
    return __builtin_amdgcn_mfma_f32_16x16x32_bf16(a, b, c, 0, 0, 0);
}
__device__ __forceinline__ float ex2(float x) { return __builtin_amdgcn_exp2f(x); }
__device__ __forceinline__ float rcp(float x) { return __builtin_amdgcn_rcpf(x); }
__device__ __forceinline__ unsigned short bf16r(float x) {
    return __builtin_bit_cast(unsigned short, __float2bfloat16(x));
}
// barrier that waits ONLY lgkmcnt (LDS) — global prefetch stays in flight.
__device__ __forceinline__ void lds_barrier() {
    asm volatile("s_waitcnt lgkmcnt(0)\n\ts_barrier" ::: "memory");
}
// bank-conflict row swizzle for the h transpose tile (writer+reader must agree)
__device__ __forceinline__ int rowswz(int L) {
    return L ^ (((L >> 4) & 1) << 1) ^ ((L >> 3) & 1);
}

// ---------- sort each node's 32 neighbors ascending; store transposed per 16-node group ----------
__global__ void sort_nbrs_kernel(const int* __restrict__ nbr, int* __restrict__ nbrT) {
    int n = blockIdx.x * blockDim.x + threadIdx.x;
    if (n >= NN) return;
    int v[32];
    const int4* src = (const int4*)(nbr + n * 32);
    #pragma unroll
    for (int i = 0; i < 8; i++) {
        int4 t = src[i];
        v[4*i] = t.x; v[4*i+1] = t.y; v[4*i+2] = t.z; v[4*i+3] = t.w;
    }
    #pragma unroll
    for (int k = 2; k <= 32; k <<= 1)
        #pragma unroll
        for (int j = k >> 1; j > 0; j >>= 1)
            #pragma unroll
            for (int i = 0; i < 32; i++) {
                int ixj = i ^ j;
                if (ixj > i) {
                    bool up = (i & k) == 0;
                    int a = v[i], b = v[ixj];
                    bool sw = up ? (a > b) : (a < b);
                    if (sw) { v[i] = b; v[ixj] = a; }
                }
            }
    int g = n >> 4, m = n & 15;
    int base = g * 512 + m;      // nbrT[g][t][m]
    #pragma unroll
    for (int t = 0; t < 32; t++) nbrT[base + t * 16] = v[t];
}

// ---------- prep: bf16 weight repack (log2e pre-folded), bias sums, padded x ----------
#define PREP_TOT (49152 + 49152 + 12288 + 12288 + 768 + 640000)
__global__ void prep_kernel(const float* __restrict__ x,
    const float* __restrict__ Wih0, const float* __restrict__ Whh0,
    const float* __restrict__ bih0, const float* __restrict__ bhh0, const float* __restrict__ Wl0,
    const float* __restrict__ Wih1, const float* __restrict__ Whh1,
    const float* __restrict__ bih1, const float* __restrict__ bhh1, const float* __restrict__ Wl1,
    const float* __restrict__ Wih2, const float* __restrict__ Whh2,
    const float* __restrict__ bih2, const float* __restrict__ bhh2, const float* __restrict__ Wl2,
    unsigned short* __restrict__ Wih_p, unsigned short* __restrict__ Whh_p,
    unsigned short* __restrict__ Wlx_p, unsigned short* __restrict__ Wlh_p,
    float* __restrict__ bsum, unsigned short* __restrict__ x32)
{
    for (int i = blockIdx.x * 256 + threadIdx.x; i < PREP_TOT; i += gridDim.x * 256) {
        int j = i;
        if (j < 49152) {                       // Wih_p: [col][k], layer0 K=32 padded from 3
            int l = j >> 14, e = j & 16383;
            if (l == 0) {
                if (e < 8192) {
                    int col = e >> 5, k = e & 31;
                    float sc = (col >= 128 && col < 192) ? TWOLOG2E : LOG2E;
                    float v = (k < 3) ? Wih0[col*3 + k] * sc : 0.f;
                    Wih_p[e] = bf16r(v);
                }
            } else {
                int col = e >> 6, k = e & 63;
                const float* W = (l == 1) ? Wih1 : Wih2;
                float sc = (col >= 128 && col < 192) ? TWOLOG2E : LOG2E;
                Wih_p[l*16384 + e] = bf16r(W[col*64 + k] * sc);
            }
            continue;
        }
        j -= 49152;
        if (j < 49152) {                       // Whh_p
            int l = j >> 14, e = j & 16383;
            int col = e >> 6, k = e & 63;
            const float* W = (l == 0) ? Whh0 : ((l == 1) ? Whh1 : Whh2);
            float sc = (col >= 128 && col < 192) ? TWOLOG2E : LOG2E;
            Whh_p[l*16384 + e] = bf16r(W[col*64 + k] * sc);
            continue;
        }
        j -= 49152;
        if (j < 12288) {                       // Wlx_p, layer0 K=32 padded from 3
            int l = j >> 12, e = j & 4095;
            if (l == 0) {
                if (e < 2048) {
                    int col = e >> 5, k = e & 31;
                    float v = (k < 3) ? Wl0[col*67 + k] : 0.f;
                    Wlx_p[e] = bf16r(v);
                }
            } else {
                int col = e >> 6, k = e & 63;
                const float* W = (l == 1) ? Wl1 : Wl2;
                Wlx_p[l*4096 + e] = bf16r(W[col*128 + k]);
            }
            continue;
        }
        j -= 12288;
        if (j < 12288) {                       // Wlh_p
            int l = j >> 12, e = j & 4095;
            int col = e >> 6, k = e & 63;
            float v = (l == 0) ? Wl0[col*67 + 3 + k]
                               : ((l == 1) ? Wl1 : Wl2)[col*128 + 64 + k];
            Wlh_p[l*4096 + e] = bf16r(v);
            continue;
        }
        j -= 12288;
        if (j < 768) {                         // bsum = (b_ih + b_hh) * scale
            int l = j >> 8, col = j & 255;
            const float* bi = (l == 0) ? bih0 : ((l == 1) ? bih1 : bih2);
            const float* bh = (l == 0) ? bhh0 : ((l == 1) ? bhh1 : bhh2);
            float sc = (col >= 128 && col < 192) ? TWOLOG2E : LOG2E;
            bsum[l*256 + col] = (bi[col] + bh[col]) * sc;
            continue;
        }
        j -= 768;
        {                                      // x32: padded bf16 node features [n][32]
            int n = j >> 5, k = j & 31;
            x32[j] = bf16r((k < 3) ? x[n*3 + k] : 0.f);
        }
    }
}

// ---------- fused LSTM-aggregate + combine (+head), MFMA version ----------
// 4 waves/block, one 16-node group per block. Wave w owns units [16w,16w+16) with ALL
// four gate tiles (cols 64*g + 16w + c) -> pointwise is wave-local, no gate exchange.
// Only cross-wave sync: h transpose via double-buffered sA, one lgkm-only barrier/step.
template<int XKC, int LASTL>
__global__ __launch_bounds__(256, 3)
void lstm_mfma_kernel(const unsigned short* __restrict__ xsrc,  // bf16 rows, stride XKC*32 shorts
                      const int* __restrict__ nbrT,
                      const unsigned short* __restrict__ Wih,   // bf16 [256][XKC*32]
                      const unsigned short* __restrict__ Whh,   // bf16 [256][64]
                      const float* __restrict__ bsum,           // [256] prescaled
                      const unsigned short* __restrict__ Wlx,   // bf16 [64][XKC*32]
                      const unsigned short* __restrict__ Wlh,   // bf16 [64][64]
                      const float* __restrict__ bl,             // [64]
                      const float* __restrict__ W_out,          // [64] (LASTL only)
                      const float* __restrict__ b_out,          // [1]  (LASTL only)
                      void* __restrict__ hout)                  // bf16[n][64] or float[n] (LASTL)
{
    __shared__ unsigned short sA[2][1024];   // h transpose, A-frag rows (swizzled), dbuf
    __shared__ float sRed[64];               // head partial sums (LASTL)

    const int w    = threadIdx.x >> 6;       // 0..3
    const int lane = threadIdx.x & 63;
    const int q    = lane >> 4;
    const int c    = lane & 15;
    const int XS   = XKC * 32;

    const int g = blockIdx.x;
    const int node0 = g * 16;
    const int* nbg = nbrT + g * 512;

    // persistent weight fragments: tile t4 = gate, col = 64*t4 + 16w + c, k = 32kc+8q+j
    short8 fWih[4][XKC];
    short8 fWhh[4][2];
    float  biasv[4];
    #pragma unroll
    for (int t4 = 0; t4 < 4; t4++) {
        int col = 64*t4 + 16*w + c;
        biasv[t4] = bsum[col];
        #pragma unroll
        for (int kc = 0; kc < XKC; kc++)
            fWih[t4][kc] = *(const short8*)(Wih + col*XS + kc*32 + q*8);
        #pragma unroll
        for (int kc = 0; kc < 2; kc++)
            fWhh[t4][kc] = *(const short8*)(Whh + col*64 + kc*32 + q*8);
    }

    float cst[4] = {0.f, 0.f, 0.f, 0.f};
    short8 hA[2] = {};

    int idx_cur = nbg[c];
    int idx_nxt = nbg[16 + c];
    short8 xg[XKC];
    #pragma unroll
    for (int kc = 0; kc < XKC; kc++)
        xg[kc] = *(const short8*)(xsrc + (long)idx_cur * XS + kc*32 + q*8);

    #pragma unroll 1
    for (int t = 0; t < 32; t++) {
        floatx4 acc[4];
        #pragma unroll
        for (int t4 = 0; t4 < 4; t4++) {
            floatx4 a; a[0] = biasv[t4]; a[1] = biasv[t4]; a[2] = biasv[t4]; a[3] = biasv[t4];
            acc[t4] = a;
        }
        if (t > 0) {
            #pragma unroll
            for (int t4 = 0; t4 < 4; t4++) {
                acc[t4] = MF(hA[0], fWhh[t4][0], acc[t4]);
                acc[t4] = MF(hA[1], fWhh[t4][1], acc[t4]);
            }
        }
        #pragma unroll
        for (int t4 = 0; t4 < 4; t4++)
            #pragma unroll
            for (int kc = 0; kc < XKC; kc++)
                acc[t4] = MF(xg[kc], fWih[t4][kc], acc[t4]);

        // prefetch next step's gathered rows (stays in flight across the lgkm-only barrier)
        if (t < 31) {
            #pragma unroll
            for (int kc = 0; kc < XKC; kc++)
                xg[kc] = *(const short8*)(xsrc + (long)idx_nxt * XS + kc*32 + q*8);
            int tn = (t + 2 < 32) ? t + 2 : 31;
            idx_nxt = nbg[tn*16 + c];
        }

        // pointwise LSTM cell; lane cells: node m=4q+r, unit u=16w+c (all 4 gates local)
        unsigned short* sAb = sA[t & 1];
        const int u = 16*w + c;
        #pragma unroll
        for (int r = 0; r < 4; r++) {
            float gi = acc[0][r], gf = acc[1][r], gg = acc[2][r], go = acc[3][r];
            float ei = ex2(-gi);
            float ef = ex2(-gf);
            float eo = ex2(-go);
            float eg = ex2(-__builtin_fabsf(gg));
            float iG = __builtin_copysignf(1.f - eg, gg) * rcp((1.f + ei) * (1.f + eg));
            float cm = fmaf(cst[r], rcp(1.f + ef), iG);
            cst[r] = cm;
            float ec = ex2(-TWOLOG2E * __builtin_fabsf(cm));
            float h  = __builtin_copysignf(1.f - ec, cm) * rcp((1.f + eo) * (1.f + ec));
            int row = (4*q + r) + 16*(u >> 3);
            sAb[rowswz(row)*8 + (u & 7)] = bf16r(h);
        }
        lds_barrier();
        hA[0] = *(const short8*)(sA[t & 1] + rowswz(lane)*8);
        hA[1] = *(const short8*)(sA[t & 1] + 512 + rowswz(lane)*8);
    }

    // ---- combine: relu([h_in, agg] @ Wl^T + bl); agg frags = hA (final h) ----
    const int col = 16*w + c;
    short8 fx[XKC], fh[2];
    float blv = bl[col];
    #pragma unroll
    for (int kc = 0; kc < XKC; kc++)
        fx[kc] = *(const short8*)(Wlx + col*XS + kc*32 + q*8);
    fh[0] = *(const short8*)(Wlh + col*64 + q*8);
    fh[1] = *(const short8*)(Wlh + col*64 + 32 + q*8);
    short8 hin[XKC];
    #pragma unroll
    for (int kc = 0; kc < XKC; kc++)
        hin[kc] = *(const short8*)(xsrc + (long)(node0 + c) * XS + kc*32 + q*8);

    floatx4 a; a[0] = blv; a[1] = blv; a[2] = blv; a[3] = blv;
    #pragma unroll
    for (int kc = 0; kc < XKC; kc++) a = MF(hin[kc], fx[kc], a);
    a = MF(hA[0], fh[0], a);
    a = MF(hA[1], fh[1], a);

    if (!LASTL) {
        #pragma unroll
        for (int r = 0; r < 4; r++)
            ((unsigned short*)hout)[(node0 + 4*q + r) * 64 + col] = bf16r(fmaxf(a[r], 0.f));
    } else {
        // fused head: out[n] = sum_u relu_comb[n][u] * W_out[u] + b_out
        float wo = W_out[col];
        float p[4];
        #pragma unroll
        for (int r = 0; r < 4; r++) p[r] = fmaxf(a[r], 0.f) * wo;
        #pragma unroll
        for (int d = 1; d < 16; d <<= 1) {
            #pragma unroll
            for (int r = 0; r < 4; r++) p[r] += __shfl_xor(p[r], d);
        }
        if (c == 0) {
            #pragma unroll
            for (int r = 0; r < 4; r++) sRed[w*16 + 4*q + r] = p[r];
        }
        lds_barrier();
        if (w == 0 && lane < 16)
            ((float*)hout)[node0 + lane] =
                sRed[lane] + sRed[16 + lane] + sRed[32 + lane] + sRed[48 + lane] + b_out[0];
    }
}

extern "C" void kernel_launch(void* const* d_in, const int* in_sizes, int n_in,
                              void* d_out, int out_size, void* d_ws, size_t ws_size,
                              hipStream_t stream) {
    (void)in_sizes; (void)n_in; (void)out_size; (void)ws_size;
    const float* node_features = (const float*)d_in[0];
    const int*   nbr           = (const int*)d_in[1];
    const float* Wih[3] = {(const float*)d_in[2],  (const float*)d_in[8],  (const float*)d_in[14]};
    const float* Whh[3] = {(const float*)d_in[3],  (const float*)d_in[9],  (const float*)d_in[15]};
    const float* bih[3] = {(const float*)d_in[4],  (const float*)d_in[10], (const float*)d_in[16]};
    const float* bhh[3] = {(const float*)d_in[5],  (const float*)d_in[11], (const float*)d_in[17]};
    const float* Wl[3]  = {(const float*)d_in[6],  (const float*)d_in[12], (const float*)d_in[18]};
    const float* bl[3]  = {(const float*)d_in[7],  (const float*)d_in[13], (const float*)d_in[19]};
    const float* W_out  = (const float*)d_in[20];
    const float* b_out  = (const float*)d_in[21];

    char* ws = (char*)d_ws;
    int*            nbrT  = (int*)ws;                               // 2,560,000 B
    unsigned short* x32   = (unsigned short*)(ws + 2560000);        // 1,280,000 B
    unsigned short* hb1   = (unsigned short*)(ws + 3840000);        // 2,560,000 B
    unsigned short* hb2   = (unsigned short*)(ws + 6400000);        // 2,560,000 B
    unsigned short* Wih_p = (unsigned short*)(ws + 8960000);        // 98,304 B
    unsigned short* Whh_p = (unsigned short*)(ws + 9058304);        // 98,304 B
    unsigned short* Wlx_p = (unsigned short*)(ws + 9156608);        // 24,576 B
    unsigned short* Wlh_p = (unsigned short*)(ws + 9181184);        // 24,576 B
    float*          bsum  = (float*)(ws + 9205760);                 // 3,072 B

    prep_kernel<<<1024, 256, 0, stream>>>(node_features,
        Wih[0], Whh[0], bih[0], bhh[0], Wl[0],
        Wih[1], Whh[1], bih[1], bhh[1], Wl[1],
        Wih[2], Whh[2], bih[2], bhh[2], Wl[2],
        Wih_p, Whh_p, Wlx_p, Wlh_p, bsum, x32);
    sort_nbrs_kernel<<<(NN + 255) / 256, 256, 0, stream>>>(nbr, nbrT);

    lstm_mfma_kernel<1, 0><<<NG, 256, 0, stream>>>(x32, nbrT,
        Wih_p,         Whh_p,         bsum,       Wlx_p,        Wlh_p,        bl[0],
        nullptr, nullptr, hb1);
    lstm_mfma_kernel<2, 0><<<NG, 256, 0, stream>>>(hb1, nbrT,
        Wih_p + 16384, Whh_p + 16384, bsum + 256, Wlx_p + 4096, Wlh_p + 4096, bl[1],
        nullptr, nullptr, hb2);
    lstm_mfma_kernel<2, 1><<<NG, 256, 0, stream>>>(hb2, nbrT,
        Wih_p + 32768, Whh_p + 32768, bsum + 512, Wlx_p + 8192, Wlh_p + 8192, bl[2],
        W_out, b_out, (float*)d_out);
}